// Round 9
// baseline (1265.301 us; speedup 1.0000x reference)
//
#include <hip/hip_runtime.h>

// ============ CSR build (both directions, one pass, no global atomics) ============
#define CSR_B 128

__global__ __launch_bounds__(256) void k_hist2(const int* __restrict__ eidx, int E, int N,
                                               int* __restrict__ partial_d,
                                               int* __restrict__ partial_s) {
  extern __shared__ unsigned int hist[];  // [2*nw]
  int nw = (N + 1) >> 1;
  for (int i = threadIdx.x; i < 2 * nw; i += blockDim.x) hist[i] = 0u;
  __syncthreads();
  const int* src = eidx;
  const int* dst = eidx + E;
  int chunk = (E + CSR_B - 1) / CSR_B;
  int beg = blockIdx.x * chunk, end = min(E, beg + chunk);
  for (int e = beg + threadIdx.x; e < end; e += blockDim.x) {
    int d = dst[e];
    atomicAdd(&hist[d >> 1], 1u << ((d & 1) * 16));
    int s = src[e];
    atomicAdd(&hist[nw + (s >> 1)], 1u << ((s & 1) * 16));
  }
  __syncthreads();
  for (int i = threadIdx.x; i < N; i += blockDim.x) {
    partial_d[(size_t)blockIdx.x * N + i] = (int)((hist[i >> 1] >> ((i & 1) * 16)) & 0xFFFFu);
    partial_s[(size_t)blockIdx.x * N + i] = (int)((hist[nw + (i >> 1)] >> ((i & 1) * 16)) & 0xFFFFu);
  }
}

__global__ __launch_bounds__(256) void k_colscan2(int* __restrict__ partial_d,
                                                  int* __restrict__ cnt_d,
                                                  int* __restrict__ partial_s,
                                                  int* __restrict__ cnt_s, int N) {
  int g = blockIdx.x * blockDim.x + threadIdx.x;
  int* partial;
  int* cnt;
  int bin;
  if (g < N) { partial = partial_d; cnt = cnt_d; bin = g; }
  else if (g < 2 * N) { partial = partial_s; cnt = cnt_s; bin = g - N; }
  else return;
  int run = 0;
  for (int b = 0; b < CSR_B; ++b) {
    int t = partial[(size_t)b * N + bin];
    partial[(size_t)b * N + bin] = run;
    run += t;
  }
  cnt[bin] = run;
}

__device__ __forceinline__ void scan_one(const int* __restrict__ cnt, int* __restrict__ rp,
                                         int N, int* sums) {
  int t = threadIdx.x;
  int chunk = (N + 1023) / 1024;
  int beg = t * chunk, end = min(N, beg + chunk);
  int s = 0;
  for (int i = beg; i < end; ++i) s += cnt[i];
  sums[t] = s;
  __syncthreads();
  for (int off = 1; off < 1024; off <<= 1) {
    int v = (t >= off) ? sums[t - off] : 0;
    __syncthreads();
    sums[t] += v;
    __syncthreads();
  }
  int run = (t > 0) ? sums[t - 1] : 0;
  if (t == 0) rp[0] = 0;
  for (int i = beg; i < end; ++i) { run += cnt[i]; rp[i + 1] = run; }
}

__global__ __launch_bounds__(1024) void k_scan2both(const int* __restrict__ cnt_d,
                                                    int* __restrict__ rp_d,
                                                    const int* __restrict__ cnt_s,
                                                    int* __restrict__ rp_s, int N) {
  __shared__ int sums[1024];
  scan_one(cnt_d, rp_d, N, sums);
  __syncthreads();
  scan_one(cnt_s, rp_s, N, sums);
}

__global__ __launch_bounds__(256) void k_scatter2(
    const int* __restrict__ eidx, int E, int N,
    const int* __restrict__ partial_d, const int* __restrict__ rp_d, int* __restrict__ csr_src,
    const int* __restrict__ partial_s, const int* __restrict__ rp_s, int* __restrict__ csr_dst) {
  extern __shared__ unsigned int cur[];  // [2*nw]
  int nw = (N + 1) >> 1;
  for (int i = threadIdx.x; i < 2 * nw; i += blockDim.x) cur[i] = 0u;
  __syncthreads();
  const int* src = eidx;
  const int* dst = eidx + E;
  int chunk = (E + CSR_B - 1) / CSR_B;
  int beg = blockIdx.x * chunk, end = min(E, beg + chunk);
  for (int e = beg + threadIdx.x; e < end; e += blockDim.x) {
    int d = dst[e], s = src[e];
    int shd = (d & 1) * 16;
    unsigned int old = atomicAdd(&cur[d >> 1], 1u << shd);
    csr_src[rp_d[d] + partial_d[(size_t)blockIdx.x * N + d] + (int)((old >> shd) & 0xFFFFu)] = s;
    int shs = (s & 1) * 16;
    unsigned int old2 = atomicAdd(&cur[nw + (s >> 1)], 1u << shs);
    csr_dst[rp_s[s] + partial_s[(size_t)blockIdx.x * N + s] + (int)((old2 >> shs) & 0xFFFFu)] = d;
  }
}

// ============ weights prep ============
__global__ void k_build_w(const float* __restrict__ W_msg, const float* __restrict__ W_self,
                          const float* __restrict__ b_msg, float* __restrict__ Wcat,
                          float* __restrict__ bcat) {
  int idx = blockIdx.x * blockDim.x + threadIdx.x;  // 256*256
  int k = idx >> 8, j = idx & 255;
  Wcat[idx] = (j < 128) ? W_msg[k * 128 + j] : W_self[k * 128 + (j - 128)];
  if (idx < 256) bcat[idx] = (idx < 128) ? b_msg[idx] : 0.0f;
}

// ============ encode: x[:,0:128] = relu([pos,sfeat]@W_enc + b_enc) ============
__global__ __launch_bounds__(256) void k_encode(
    const float* __restrict__ pos, const float* __restrict__ sfeat,
    const float* __restrict__ W_enc, const float* __restrict__ b_enc,
    float* __restrict__ x, int N) {
  int idx = blockIdx.x * blockDim.x + threadIdx.x;
  int n = idx >> 5, d4 = (idx & 31) << 2;
  if (n >= N) return;
  float p = pos[n], sf = sfeat[n];
  float4 we0 = *reinterpret_cast<const float4*>(&W_enc[d4]);
  float4 we1 = *reinterpret_cast<const float4*>(&W_enc[128 + d4]);
  float4 be  = *reinterpret_cast<const float4*>(&b_enc[d4]);
  float4 z;
  z.x = fmaxf(fmaf(p, we0.x, fmaf(sf, we1.x, be.x)), 0.f);
  z.y = fmaxf(fmaf(p, we0.y, fmaf(sf, we1.y, be.y)), 0.f);
  z.z = fmaxf(fmaf(p, we0.z, fmaf(sf, we1.z, be.z)), 0.f);
  z.w = fmaxf(fmaf(p, we0.w, fmaf(sf, we1.w, be.w)), 0.f);
  *reinterpret_cast<float4*>(&x[(size_t)n * 256 + d4]) = z;
}

// ============ GEMM (barrier-free k-loop): xw = x @ Wcat + bcat ============
// B col-panel (KT x 64 = 32/64 KB) staged in LDS ONCE; A rows streamed from
// global (x is contiguous [N][256]) with a 2-stage register pipeline.
// Block 256 thr, BM=128, BN=64; thread = 8 rows x 4 cols; per k: 1 ds_read_b128
// + 32 FMA -> VALU-bound at 8 waves/CU. KT=128 for it0 (h half never read).
template <int KT>
__global__ __launch_bounds__(256) void k_gemm_nb(
    const float* __restrict__ x, const float* __restrict__ B,
    const float* __restrict__ bias, float* __restrict__ C, int M) {
  __shared__ float Bs[KT][64];
  const int m0 = blockIdx.x * 128, n0 = blockIdx.y * 64;
  const int t = threadIdx.x;
  // stage B panel (coalesced; KT*16 float4s)
  for (int idx = t; idx < KT * 16; idx += 256) {
    int row = idx >> 4, c4 = (idx & 15) << 2;
    *reinterpret_cast<float4*>(&Bs[row][c4]) =
        *reinterpret_cast<const float4*>(&B[(size_t)row * 256 + n0 + c4]);
  }
  __syncthreads();  // the only barrier

  const int c4 = (t & 15) << 2;          // col within panel
  const int r0 = m0 + (t >> 4) * 8;      // first of 8 rows
  int rows[8];
#pragma unroll
  for (int i = 0; i < 8; ++i) rows[i] = min(r0 + i, M - 1);  // clamp (store guarded)

  float4 a_[8], b_[8];
  float acc[8][4] = {};
#define LOADA(buf, kk)                                                                \
  _Pragma("unroll") for (int i = 0; i < 8; ++i) buf[i] =                              \
      *reinterpret_cast<const float4*>(&x[(size_t)rows[i] * 256 + (kk)]);
#define COMP(buf, kk)                                                                 \
  _Pragma("unroll") for (int j = 0; j < 4; ++j) {                                     \
    float4 b4 = *reinterpret_cast<const float4*>(&Bs[(kk) + j][c4]);                  \
    _Pragma("unroll") for (int i = 0; i < 8; ++i) {                                   \
      float av = (j == 0) ? buf[i].x : (j == 1) ? buf[i].y : (j == 2) ? buf[i].z      \
                                                                      : buf[i].w;     \
      acc[i][0] = fmaf(av, b4.x, acc[i][0]);                                          \
      acc[i][1] = fmaf(av, b4.y, acc[i][1]);                                          \
      acc[i][2] = fmaf(av, b4.z, acc[i][2]);                                          \
      acc[i][3] = fmaf(av, b4.w, acc[i][3]);                                          \
    }                                                                                 \
  }

  LOADA(a_, 0);
  for (int k0 = 0; k0 < KT; k0 += 8) {
    LOADA(b_, k0 + 4);
    COMP(a_, k0);
    if (k0 + 8 < KT) { LOADA(a_, k0 + 8); }
    COMP(b_, k0 + 4);
  }
#undef LOADA
#undef COMP
  float4 bi = *reinterpret_cast<const float4*>(&bias[n0 + c4]);
#pragma unroll
  for (int i = 0; i < 8; ++i) {
    int row = r0 + i;
    if (row < M) {
      float4 o = make_float4(acc[i][0] + bi.x, acc[i][1] + bi.y, acc[i][2] + bi.z,
                             acc[i][3] + bi.w);
      *reinterpret_cast<float4*>(&C[(size_t)row * 256 + n0 + c4]) = o;
    }
  }
}

// ============ aggmax: feature-chunked for per-XCD L2 residence ============
__global__ __launch_bounds__(256) void k_aggmax(
    const float* __restrict__ xw, const int* __restrict__ row_ptr,
    const int* __restrict__ csr_src, float* __restrict__ agg, int N, int Nh) {
  const int cx = blockIdx.x & 7;
  const int chunk = cx & 3;
  const int half = cx >> 2;
  const int hw = threadIdx.x >> 5;
  const int sub = threadIdx.x & 31;
  const int node = half * Nh + blockIdx.y * 8 + hw;
  const int hi = half ? N : Nh;
  if (node >= hi) return;
  const float* base = xw + chunk * 32 + sub;
  const int beg = row_ptr[node], end = row_ptr[node + 1];
  float m0 = 0.f, m1 = 0.f, m2 = 0.f, m3 = 0.f;
  int i = beg;
  for (; i + 3 < end; i += 4) {
    int e0 = csr_src[i], e1 = csr_src[i + 1], e2 = csr_src[i + 2], e3 = csr_src[i + 3];
    float f0 = base[(size_t)e0 * 256];
    float f1 = base[(size_t)e1 * 256];
    float f2 = base[(size_t)e2 * 256];
    float f3 = base[(size_t)e3 * 256];
    m0 = fmaxf(m0, f0); m1 = fmaxf(m1, f1);
    m2 = fmaxf(m2, f2); m3 = fmaxf(m3, f3);
  }
  for (; i < end; ++i) m0 = fmaxf(m0, base[(size_t)csr_src[i] * 256]);
  m0 = fmaxf(fmaxf(m0, m1), fmaxf(m2, m3));
  agg[(size_t)node * 128 + chunk * 32 + sub] = m0;
}

// ==== update GEMM: h = relu(agg@W_agg + self + b_upd) -> x[:,128:256]; fused u,v ====
__global__ __launch_bounds__(256) void k_update2(
    const float* __restrict__ agg, const float* __restrict__ W_agg,
    const float* __restrict__ b_upd, const float* __restrict__ xw,
    const float* __restrict__ W_dec, const float* __restrict__ b_dec,
    float* __restrict__ x, float* __restrict__ u, float* __restrict__ v, int M) {
  __shared__ float AsT[32][33];   // [k][row] (transposed for b128 A reads)
  __shared__ float Bs[32][128];
  const int m0 = blockIdx.x * 32;
  const int t = threadIdx.x;
  const int ty = t >> 5, tx = t & 31;
  const int lar = t >> 3, lac = (t & 7) << 2;
  float acc[4][4] = {};
  for (int k0 = 0; k0 < 128; k0 += 32) {
    {
      float4 av = make_float4(0.f, 0.f, 0.f, 0.f);
      int row = m0 + lar;
      if (row < M) av = *reinterpret_cast<const float4*>(&agg[(size_t)row * 128 + k0 + lac]);
      AsT[lac + 0][lar] = av.x;
      AsT[lac + 1][lar] = av.y;
      AsT[lac + 2][lar] = av.z;
      AsT[lac + 3][lar] = av.w;
#pragma unroll
      for (int p = 0; p < 4; ++p) {
        int br = (t >> 5) + p * 8;
        *reinterpret_cast<float4*>(&Bs[br][tx * 4]) =
            *reinterpret_cast<const float4*>(&W_agg[(size_t)(k0 + br) * 128 + tx * 4]);
      }
    }
    __syncthreads();
#pragma unroll
    for (int k = 0; k < 32; ++k) {
      float4 a4 = *reinterpret_cast<const float4*>(&AsT[k][ty * 4]);
      float4 b4 = *reinterpret_cast<const float4*>(&Bs[k][tx * 4]);
      const float aa[4] = {a4.x, a4.y, a4.z, a4.w};
      const float bb[4] = {b4.x, b4.y, b4.z, b4.w};
#pragma unroll
      for (int j = 0; j < 4; ++j)
#pragma unroll
        for (int c = 0; c < 4; ++c) acc[j][c] = fmaf(aa[j], bb[c], acc[j][c]);
    }
    __syncthreads();
  }
  const float4 bu4 = *reinterpret_cast<const float4*>(&b_upd[tx * 4]);
  const float4 wdu = *reinterpret_cast<const float4*>(&W_dec[tx * 4]);
  const float4 wdv = *reinterpret_cast<const float4*>(&W_dec[128 + tx * 4]);
  const float bd = b_dec[0];
#pragma unroll
  for (int j = 0; j < 4; ++j) {
    int row = m0 + ty * 4 + j;
    if (row >= M) continue;
    float4 sf = *reinterpret_cast<const float4*>(&xw[(size_t)row * 256 + 128 + tx * 4]);
    float4 h4;
    h4.x = fmaxf(acc[j][0] + sf.x + bu4.x, 0.f);
    h4.y = fmaxf(acc[j][1] + sf.y + bu4.y, 0.f);
    h4.z = fmaxf(acc[j][2] + sf.z + bu4.z, 0.f);
    h4.w = fmaxf(acc[j][3] + sf.w + bu4.w, 0.f);
    *reinterpret_cast<float4*>(&x[(size_t)row * 256 + 128 + tx * 4]) = h4;  // h into x
    float up = h4.x * wdu.x + h4.y * wdu.y + h4.z * wdu.z + h4.w * wdu.w;
    float vp = h4.x * wdv.x + h4.y * wdv.y + h4.z * wdv.z + h4.w * wdv.w;
#pragma unroll
    for (int m = 16; m > 0; m >>= 1) {
      up += __shfl_xor(up, m);
      vp += __shfl_xor(vp, m);
    }
    if (tx == 0) {
      u[row] = up + bd;
      v[row] = vp;
    }
  }
}

// ============ fused losses: edge BCE partials + node y/max + y-BCE partials ============
#define GB 512
__global__ __launch_bounds__(256) void k_losses(
    const int* __restrict__ src, const int* __restrict__ dst, const float* __restrict__ u,
    const float* __restrict__ v, const int* __restrict__ tgt, const int* __restrict__ row_ptr,
    const int* __restrict__ csr_src, const int* __restrict__ row_ptr2,
    const int* __restrict__ csr_dst, const int* __restrict__ reach_row,
    float* __restrict__ ybuf, float* __restrict__ yout, int write_out,
    double* __restrict__ pe_slot, double* __restrict__ py_slot, int E, int N) {
  __shared__ double wsum[4];
  double term = 0.0;
  for (int e = blockIdx.x * blockDim.x + threadIdx.x; e < E; e += GB * 256) {
    float l = u[src[e]] + v[dst[e]];
    float a = 1.0f / (1.0f + expf(-l));
    float t = (float)tgt[e];
    float lp = fmaxf(logf(a), -100.0f);
    float l1 = fmaxf(logf(1.0f - a), -100.0f);
    term += (double)(t * lp + (1.0f - t) * l1);
  }
#pragma unroll
  for (int off = 32; off > 0; off >>= 1) term += __shfl_down(term, off);
  if ((threadIdx.x & 63) == 0) wsum[threadIdx.x >> 6] = term;
  __syncthreads();
  if (threadIdx.x == 0) pe_slot[blockIdx.x] = wsum[0] + wsum[1] + wsum[2] + wsum[3];
  __syncthreads();
  double c = 0.0;
  for (int n = blockIdx.x * blockDim.x + threadIdx.x; n < N; n += GB * 256) {
    float mu = -INFINITY, mv = -INFINITY;
    const int b1 = row_ptr[n], e1 = row_ptr[n + 1];
    for (int i = b1; i < e1; ++i) mu = fmaxf(mu, u[csr_src[i]]);
    const int b2 = row_ptr2[n], e2 = row_ptr2[n + 1];
    for (int i = b2; i < e2; ++i) mv = fmaxf(mv, v[csr_dst[i]]);
    float m = fmaxf(mu + v[n], u[n] + mv);
    float a = 1.0f / (1.0f + expf(-m));
    float yv = (a >= 0.8f) ? 1.0f : 0.0f;
    ybuf[n] = yv;
    if (write_out) yout[n] = yv;
    if ((float)reach_row[n] != yv) c = 100.0;
  }
#pragma unroll
  for (int off = 32; off > 0; off >>= 1) c += __shfl_down(c, off);
  if ((threadIdx.x & 63) == 0) wsum[threadIdx.x >> 6] = c;
  __syncthreads();
  if (threadIdx.x == 0) py_slot[blockIdx.x] = wsum[0] + wsum[1] + wsum[2] + wsum[3];
}

__global__ void k_final(const double* __restrict__ pe, const double* __restrict__ py,
                        float* __restrict__ out4, int N, int E, int T) {
  __shared__ double le[8], ly[8];
  int lane = threadIdx.x;  // 64 threads
  for (int it = 0; it < T; ++it) {
    double s = 0.0;
    for (int i = lane; i < GB; i += 64) s += pe[(size_t)it * GB + i];
#pragma unroll
    for (int off = 32; off > 0; off >>= 1) s += __shfl_down(s, off);
    if (lane == 0) le[it] = s;
    double s2 = 0.0;
    for (int i = lane; i < GB; i += 64) s2 += py[(size_t)it * GB + i];
#pragma unroll
    for (int off = 32; off > 0; off >>= 1) s2 += __shfl_down(s2, off);
    if (lane == 0) ly[it] = s2;
  }
  __syncthreads();
  if (lane == 0) {
    float loss_x = (float)(-le[T - 1] / (double)E);
    float loss_h = 0.0f;
    for (int i = 0; i < T - 1; ++i) loss_h += (float)(-le[i] / (double)E);
    float yl_x = (float)(ly[T - 1] / (double)N);
    float yl_h = 0.0f;
    for (int i = 0; i < T - 1; ++i) yl_h += (float)(ly[i] / (double)N);
    out4[0] = loss_x;
    out4[1] = loss_h;
    out4[2] = yl_x;
    out4[3] = yl_h;
  }
}

// ============ launch ============
extern "C" void kernel_launch(void* const* d_in, const int* in_sizes, int n_in,
                              void* d_out, int out_size, void* d_ws, size_t ws_size,
                              hipStream_t stream) {
  const float* pos = (const float*)d_in[0];
  const float* s = (const float*)d_in[1];
  const int* eidx = (const int*)d_in[2];
  const int* pi = (const int*)d_in[3];
  const int* pi_h = (const int*)d_in[4];
  const int* reach = (const int*)d_in[5];
  const float* W_enc = (const float*)d_in[6];
  const float* b_enc = (const float*)d_in[7];
  const float* W_msg = (const float*)d_in[8];
  const float* b_msg = (const float*)d_in[9];
  const float* W_self = (const float*)d_in[10];
  const float* W_agg = (const float*)d_in[11];
  const float* b_upd = (const float*)d_in[12];
  const float* W_dec = (const float*)d_in[13];
  const float* b_dec = (const float*)d_in[14];

  const int N = in_sizes[0];
  const int E = in_sizes[3];
  const int T = in_sizes[4] / in_sizes[3];
  const int* src = eidx;
  const int* dst = eidx + E;

  char* w = (char*)d_ws;
  auto alloc = [&](size_t bytes) {
    char* p = w;
    w += (bytes + 255) & ~(size_t)255;
    return p;
  };
  float* x = (float*)alloc((size_t)N * 256 * 4);    // [z | h]
  float* xw = (float*)alloc((size_t)N * 256 * 4);   // [msg_pre | self_pre]
  float* agg = (float*)alloc((size_t)N * 128 * 4);
  float* Wcat = (float*)alloc(256 * 256 * 4);
  float* bcat = (float*)alloc(256 * 4);
  float* u = (float*)alloc((size_t)N * 4);
  float* v = (float*)alloc((size_t)N * 4);
  float* ybuf = (float*)alloc((size_t)N * 4);
  int* cnt_d = (int*)alloc((size_t)N * 4);
  int* cnt_s = (int*)alloc((size_t)N * 4);
  int* row_ptr = (int*)alloc((size_t)(N + 1) * 4);
  int* row_ptr2 = (int*)alloc((size_t)(N + 1) * 4);
  int* csr_src = (int*)alloc((size_t)E * 4);
  int* csr_dst = (int*)alloc((size_t)E * 4);
  int* partial_d = (int*)alloc((size_t)CSR_B * N * 4);
  int* partial_s = (int*)alloc((size_t)CSR_B * N * 4);
  double* pe = (double*)alloc((size_t)T * GB * 8);
  double* py = (double*)alloc((size_t)T * GB * 8);

  float* outy = (float*)d_out;
  float* out4 = outy + N;

  k_build_w<<<256, 256, 0, stream>>>(W_msg, W_self, b_msg, Wcat, bcat);

  const size_t lds2 = (size_t)2 * ((N + 1) >> 1) * 4;  // ~80 KB
  k_hist2<<<CSR_B, 256, lds2, stream>>>(eidx, E, N, partial_d, partial_s);
  k_colscan2<<<(2 * N + 255) / 256, 256, 0, stream>>>(partial_d, cnt_d, partial_s, cnt_s, N);
  k_scan2both<<<1, 1024, 0, stream>>>(cnt_d, row_ptr, cnt_s, row_ptr2, N);
  k_scatter2<<<CSR_B, 256, lds2, stream>>>(eidx, E, N, partial_d, row_ptr, csr_src, partial_s,
                                           row_ptr2, csr_dst);

  const int Nh = (N + 1) / 2;
  const int NB = (Nh + 7) / 8;

  const float* sfeat = s;
  for (int it = 0; it < T; ++it) {
    k_encode<<<(N * 32 + 255) / 256, 256, 0, stream>>>(pos, sfeat, W_enc, b_enc, x, N);

    dim3 g1((N + 127) / 128, 4);
    if (it == 0)
      k_gemm_nb<128><<<g1, 256, 0, stream>>>(x, Wcat, bcat, xw, N);
    else
      k_gemm_nb<256><<<g1, 256, 0, stream>>>(x, Wcat, bcat, xw, N);

    k_aggmax<<<dim3(8, NB), 256, 0, stream>>>(xw, row_ptr, csr_src, agg, N, Nh);

    k_update2<<<(N + 31) / 32, 256, 0, stream>>>(agg, W_agg, b_upd, xw, W_dec, b_dec,
                                                 x, u, v, N);

    const int* tgt = (it < T - 1) ? (pi_h + (size_t)(it + 1) * E) : pi;
    const int* rrow = (it < T - 1) ? (reach + (size_t)(it + 1) * N) : (reach + (size_t)(T - 1) * N);
    k_losses<<<GB, 256, 0, stream>>>(src, dst, u, v, tgt, row_ptr, csr_src, row_ptr2, csr_dst,
                                     rrow, ybuf, outy, (it == T - 1) ? 1 : 0,
                                     pe + (size_t)it * GB, py + (size_t)it * GB, E, N);
    sfeat = ybuf;
  }
  k_final<<<1, 64, 0, stream>>>(pe, py, out4, N, E, T);
}

// Round 10
// 642.012 us; speedup vs baseline: 1.9708x; 1.9708x over previous
//
#include <hip/hip_runtime.h>

// ============ CSR build (both directions, one pass, no global atomics) ============
#define CSR_B 128

__global__ __launch_bounds__(256) void k_hist2(const int* __restrict__ eidx, int E, int N,
                                               int* __restrict__ partial_d,
                                               int* __restrict__ partial_s) {
  extern __shared__ unsigned int hist[];  // [2*nw]
  int nw = (N + 1) >> 1;
  for (int i = threadIdx.x; i < 2 * nw; i += blockDim.x) hist[i] = 0u;
  __syncthreads();
  const int* src = eidx;
  const int* dst = eidx + E;
  int chunk = (E + CSR_B - 1) / CSR_B;
  int beg = blockIdx.x * chunk, end = min(E, beg + chunk);
  for (int e = beg + threadIdx.x; e < end; e += blockDim.x) {
    int d = dst[e];
    atomicAdd(&hist[d >> 1], 1u << ((d & 1) * 16));
    int s = src[e];
    atomicAdd(&hist[nw + (s >> 1)], 1u << ((s & 1) * 16));
  }
  __syncthreads();
  for (int i = threadIdx.x; i < N; i += blockDim.x) {
    partial_d[(size_t)blockIdx.x * N + i] = (int)((hist[i >> 1] >> ((i & 1) * 16)) & 0xFFFFu);
    partial_s[(size_t)blockIdx.x * N + i] = (int)((hist[nw + (i >> 1)] >> ((i & 1) * 16)) & 0xFFFFu);
  }
}

__global__ __launch_bounds__(256) void k_colscan2(int* __restrict__ partial_d,
                                                  int* __restrict__ cnt_d,
                                                  int* __restrict__ partial_s,
                                                  int* __restrict__ cnt_s, int N) {
  int g = blockIdx.x * blockDim.x + threadIdx.x;
  int* partial;
  int* cnt;
  int bin;
  if (g < N) { partial = partial_d; cnt = cnt_d; bin = g; }
  else if (g < 2 * N) { partial = partial_s; cnt = cnt_s; bin = g - N; }
  else return;
  int run = 0;
  for (int b = 0; b < CSR_B; ++b) {
    int t = partial[(size_t)b * N + bin];
    partial[(size_t)b * N + bin] = run;
    run += t;
  }
  cnt[bin] = run;
}

__device__ __forceinline__ void scan_one(const int* __restrict__ cnt, int* __restrict__ rp,
                                         int N, int* sums) {
  int t = threadIdx.x;
  int chunk = (N + 1023) / 1024;
  int beg = t * chunk, end = min(N, beg + chunk);
  int s = 0;
  for (int i = beg; i < end; ++i) s += cnt[i];
  sums[t] = s;
  __syncthreads();
  for (int off = 1; off < 1024; off <<= 1) {
    int v = (t >= off) ? sums[t - off] : 0;
    __syncthreads();
    sums[t] += v;
    __syncthreads();
  }
  int run = (t > 0) ? sums[t - 1] : 0;
  if (t == 0) rp[0] = 0;
  for (int i = beg; i < end; ++i) { run += cnt[i]; rp[i + 1] = run; }
}

__global__ __launch_bounds__(1024) void k_scan2both(const int* __restrict__ cnt_d,
                                                    int* __restrict__ rp_d,
                                                    const int* __restrict__ cnt_s,
                                                    int* __restrict__ rp_s, int N) {
  __shared__ int sums[1024];
  scan_one(cnt_d, rp_d, N, sums);
  __syncthreads();
  scan_one(cnt_s, rp_s, N, sums);
}

__global__ __launch_bounds__(256) void k_scatter2(
    const int* __restrict__ eidx, int E, int N,
    const int* __restrict__ partial_d, const int* __restrict__ rp_d, int* __restrict__ csr_src,
    const int* __restrict__ partial_s, const int* __restrict__ rp_s, int* __restrict__ csr_dst) {
  extern __shared__ unsigned int cur[];  // [2*nw]
  int nw = (N + 1) >> 1;
  for (int i = threadIdx.x; i < 2 * nw; i += blockDim.x) cur[i] = 0u;
  __syncthreads();
  const int* src = eidx;
  const int* dst = eidx + E;
  int chunk = (E + CSR_B - 1) / CSR_B;
  int beg = blockIdx.x * chunk, end = min(E, beg + chunk);
  for (int e = beg + threadIdx.x; e < end; e += blockDim.x) {
    int d = dst[e], s = src[e];
    int shd = (d & 1) * 16;
    unsigned int old = atomicAdd(&cur[d >> 1], 1u << shd);
    csr_src[rp_d[d] + partial_d[(size_t)blockIdx.x * N + d] + (int)((old >> shd) & 0xFFFFu)] = s;
    int shs = (s & 1) * 16;
    unsigned int old2 = atomicAdd(&cur[nw + (s >> 1)], 1u << shs);
    csr_dst[rp_s[s] + partial_s[(size_t)blockIdx.x * N + s] + (int)((old2 >> shs) & 0xFFFFu)] = d;
  }
}

// ============ weights prep ============
__global__ void k_build_w(const float* __restrict__ W_msg, const float* __restrict__ W_self,
                          const float* __restrict__ b_msg, float* __restrict__ Wcat,
                          float* __restrict__ bcat) {
  int idx = blockIdx.x * blockDim.x + threadIdx.x;  // 256*256
  int k = idx >> 8, j = idx & 255;
  Wcat[idx] = (j < 128) ? W_msg[k * 128 + j] : W_self[k * 128 + (j - 128)];
  if (idx < 256) bcat[idx] = (idx < 128) ? b_msg[idx] : 0.0f;
}

// ============ encode: x[:,0:128] = relu([pos,sfeat]@W_enc + b_enc) ============
__global__ __launch_bounds__(256) void k_encode(
    const float* __restrict__ pos, const float* __restrict__ sfeat,
    const float* __restrict__ W_enc, const float* __restrict__ b_enc,
    float* __restrict__ x, int N) {
  int idx = blockIdx.x * blockDim.x + threadIdx.x;
  int n = idx >> 5, d4 = (idx & 31) << 2;
  if (n >= N) return;
  float p = pos[n], sf = sfeat[n];
  float4 we0 = *reinterpret_cast<const float4*>(&W_enc[d4]);
  float4 we1 = *reinterpret_cast<const float4*>(&W_enc[128 + d4]);
  float4 be  = *reinterpret_cast<const float4*>(&b_enc[d4]);
  float4 z;
  z.x = fmaxf(fmaf(p, we0.x, fmaf(sf, we1.x, be.x)), 0.f);
  z.y = fmaxf(fmaf(p, we0.y, fmaf(sf, we1.y, be.y)), 0.f);
  z.z = fmaxf(fmaf(p, we0.z, fmaf(sf, we1.z, be.z)), 0.f);
  z.w = fmaxf(fmaf(p, we0.w, fmaf(sf, we1.w, be.w)), 0.f);
  *reinterpret_cast<float4*>(&x[(size_t)n * 256 + d4]) = z;
}

// ============ GEMM (barrier-free k-loop, register-disciplined) ============
// xw = x @ Wcat + bcat. B col-panel (KT x 32 = 16/32 KB) staged ONCE in LDS
// (5 blocks/CU). 128 threads = 16 row-groups x 8 col-groups; thread = 8 rows
// x 4 cols with 2-deep NAMED-register quad pipeline (no arrays -> no spill).
// Per k-quad per wave: 4 ds_read_b128 (192 cyc/CU at 4 SIMD) < 128 FMA
// (256 cyc) -> VALU-bound. x/xw padded to Npad: no guards anywhere.
__device__ __forceinline__ float comp4(const float4 v, int j) {
  return (j == 0) ? v.x : (j == 1) ? v.y : (j == 2) ? v.z : v.w;
}
__device__ __forceinline__ void fma4(const float4 b4, const float a, float* acc) {
  acc[0] = fmaf(a, b4.x, acc[0]);
  acc[1] = fmaf(a, b4.y, acc[1]);
  acc[2] = fmaf(a, b4.z, acc[2]);
  acc[3] = fmaf(a, b4.w, acc[3]);
}

template <int KT>
__global__ __launch_bounds__(128, 2) void k_gemm_bf(
    const float* __restrict__ x, const float* __restrict__ Wc,
    const float* __restrict__ bias, float* __restrict__ C) {
  __shared__ float Bs[KT][32];
  const int m0 = blockIdx.x * 128, n0 = blockIdx.y * 32;
  const int t = threadIdx.x;
  for (int idx = t; idx < KT * 8; idx += 128) {
    int row = idx >> 3, cc = (idx & 7) << 2;
    *reinterpret_cast<float4*>(&Bs[row][cc]) =
        *reinterpret_cast<const float4*>(&Wc[(size_t)row * 256 + n0 + cc]);
  }
  __syncthreads();  // the only barrier

  const int c4 = (t & 7) << 2;
  const int r0 = m0 + (t >> 3) * 8;
  const float* xp = x + (size_t)r0 * 256;
  float acc[8][4] = {};
  float4 A0, A1, A2, A3, A4, A5, A6, A7;
  float4 Q0, Q1, Q2, Q3, Q4, Q5, Q6, Q7;

#define LOADQ(R, kk)                                              \
  R##0 = *reinterpret_cast<const float4*>(xp + 0 * 256 + (kk));   \
  R##1 = *reinterpret_cast<const float4*>(xp + 1 * 256 + (kk));   \
  R##2 = *reinterpret_cast<const float4*>(xp + 2 * 256 + (kk));   \
  R##3 = *reinterpret_cast<const float4*>(xp + 3 * 256 + (kk));   \
  R##4 = *reinterpret_cast<const float4*>(xp + 4 * 256 + (kk));   \
  R##5 = *reinterpret_cast<const float4*>(xp + 5 * 256 + (kk));   \
  R##6 = *reinterpret_cast<const float4*>(xp + 6 * 256 + (kk));   \
  R##7 = *reinterpret_cast<const float4*>(xp + 7 * 256 + (kk));

#define FMAQ(R, kk)                                                        \
  {                                                                        \
    _Pragma("unroll") for (int j = 0; j < 4; ++j) {                        \
      float4 b4 = *reinterpret_cast<const float4*>(&Bs[(kk) + j][c4]);     \
      fma4(b4, comp4(R##0, j), acc[0]);                                    \
      fma4(b4, comp4(R##1, j), acc[1]);                                    \
      fma4(b4, comp4(R##2, j), acc[2]);                                    \
      fma4(b4, comp4(R##3, j), acc[3]);                                    \
      fma4(b4, comp4(R##4, j), acc[4]);                                    \
      fma4(b4, comp4(R##5, j), acc[5]);                                    \
      fma4(b4, comp4(R##6, j), acc[6]);                                    \
      fma4(b4, comp4(R##7, j), acc[7]);                                    \
    }                                                                      \
  }

  LOADQ(A, 0);
  for (int kq = 0; kq + 8 < KT; kq += 8) {
    LOADQ(Q, kq + 4);
    FMAQ(A, kq);
    LOADQ(A, kq + 8);
    FMAQ(Q, kq + 4);
  }
  LOADQ(Q, KT - 4);
  FMAQ(A, KT - 8);
  FMAQ(Q, KT - 4);
#undef LOADQ
#undef FMAQ

  float4 bi = *reinterpret_cast<const float4*>(&bias[n0 + c4]);
#pragma unroll
  for (int i = 0; i < 8; ++i) {
    float4 o = make_float4(acc[i][0] + bi.x, acc[i][1] + bi.y, acc[i][2] + bi.z,
                           acc[i][3] + bi.w);
    *reinterpret_cast<float4*>(&C[(size_t)(r0 + i) * 256 + n0 + c4]) = o;
  }
}

// ============ aggmax: feature-chunked for per-XCD L2 residence ============
__global__ __launch_bounds__(256) void k_aggmax(
    const float* __restrict__ xw, const int* __restrict__ row_ptr,
    const int* __restrict__ csr_src, float* __restrict__ agg, int N, int Nh) {
  const int cx = blockIdx.x & 7;
  const int chunk = cx & 3;
  const int half = cx >> 2;
  const int hw = threadIdx.x >> 5;
  const int sub = threadIdx.x & 31;
  const int node = half * Nh + blockIdx.y * 8 + hw;
  const int hi = half ? N : Nh;
  if (node >= hi) return;
  const float* base = xw + chunk * 32 + sub;
  const int beg = row_ptr[node], end = row_ptr[node + 1];
  float m0 = 0.f, m1 = 0.f, m2 = 0.f, m3 = 0.f;
  int i = beg;
  for (; i + 3 < end; i += 4) {
    int e0 = csr_src[i], e1 = csr_src[i + 1], e2 = csr_src[i + 2], e3 = csr_src[i + 3];
    float f0 = base[(size_t)e0 * 256];
    float f1 = base[(size_t)e1 * 256];
    float f2 = base[(size_t)e2 * 256];
    float f3 = base[(size_t)e3 * 256];
    m0 = fmaxf(m0, f0); m1 = fmaxf(m1, f1);
    m2 = fmaxf(m2, f2); m3 = fmaxf(m3, f3);
  }
  for (; i < end; ++i) m0 = fmaxf(m0, base[(size_t)csr_src[i] * 256]);
  m0 = fmaxf(fmaxf(m0, m1), fmaxf(m2, m3));
  agg[(size_t)node * 128 + chunk * 32 + sub] = m0;
}

// ==== update GEMM: h = relu(agg@W_agg + self + b_upd) -> x[:,128:256]; fused u,v ====
__global__ __launch_bounds__(256) void k_update2(
    const float* __restrict__ agg, const float* __restrict__ W_agg,
    const float* __restrict__ b_upd, const float* __restrict__ xw,
    const float* __restrict__ W_dec, const float* __restrict__ b_dec,
    float* __restrict__ x, float* __restrict__ u, float* __restrict__ v, int M) {
  __shared__ float AsT[32][33];   // [k][row] (transposed for b128 A reads)
  __shared__ float Bs[32][128];
  const int m0 = blockIdx.x * 32;
  const int t = threadIdx.x;
  const int ty = t >> 5, tx = t & 31;
  const int lar = t >> 3, lac = (t & 7) << 2;
  float acc[4][4] = {};
  for (int k0 = 0; k0 < 128; k0 += 32) {
    {
      float4 av = make_float4(0.f, 0.f, 0.f, 0.f);
      int row = m0 + lar;
      if (row < M) av = *reinterpret_cast<const float4*>(&agg[(size_t)row * 128 + k0 + lac]);
      AsT[lac + 0][lar] = av.x;
      AsT[lac + 1][lar] = av.y;
      AsT[lac + 2][lar] = av.z;
      AsT[lac + 3][lar] = av.w;
#pragma unroll
      for (int p = 0; p < 4; ++p) {
        int br = (t >> 5) + p * 8;
        *reinterpret_cast<float4*>(&Bs[br][tx * 4]) =
            *reinterpret_cast<const float4*>(&W_agg[(size_t)(k0 + br) * 128 + tx * 4]);
      }
    }
    __syncthreads();
#pragma unroll
    for (int k = 0; k < 32; ++k) {
      float4 a4 = *reinterpret_cast<const float4*>(&AsT[k][ty * 4]);
      float4 b4 = *reinterpret_cast<const float4*>(&Bs[k][tx * 4]);
      const float aa[4] = {a4.x, a4.y, a4.z, a4.w};
      const float bb[4] = {b4.x, b4.y, b4.z, b4.w};
#pragma unroll
      for (int j = 0; j < 4; ++j)
#pragma unroll
        for (int c = 0; c < 4; ++c) acc[j][c] = fmaf(aa[j], bb[c], acc[j][c]);
    }
    __syncthreads();
  }
  const float4 bu4 = *reinterpret_cast<const float4*>(&b_upd[tx * 4]);
  const float4 wdu = *reinterpret_cast<const float4*>(&W_dec[tx * 4]);
  const float4 wdv = *reinterpret_cast<const float4*>(&W_dec[128 + tx * 4]);
  const float bd = b_dec[0];
#pragma unroll
  for (int j = 0; j < 4; ++j) {
    int row = m0 + ty * 4 + j;
    if (row >= M) continue;
    float4 sf = *reinterpret_cast<const float4*>(&xw[(size_t)row * 256 + 128 + tx * 4]);
    float4 h4;
    h4.x = fmaxf(acc[j][0] + sf.x + bu4.x, 0.f);
    h4.y = fmaxf(acc[j][1] + sf.y + bu4.y, 0.f);
    h4.z = fmaxf(acc[j][2] + sf.z + bu4.z, 0.f);
    h4.w = fmaxf(acc[j][3] + sf.w + bu4.w, 0.f);
    *reinterpret_cast<float4*>(&x[(size_t)row * 256 + 128 + tx * 4]) = h4;  // h into x
    float up = h4.x * wdu.x + h4.y * wdu.y + h4.z * wdu.z + h4.w * wdu.w;
    float vp = h4.x * wdv.x + h4.y * wdv.y + h4.z * wdv.z + h4.w * wdv.w;
#pragma unroll
    for (int m = 16; m > 0; m >>= 1) {
      up += __shfl_xor(up, m);
      vp += __shfl_xor(vp, m);
    }
    if (tx == 0) {
      u[row] = up + bd;
      v[row] = vp;
    }
  }
}

// ============ fused losses: edge BCE partials + node y/max + y-BCE partials ============
#define GB 512
__global__ __launch_bounds__(256) void k_losses(
    const int* __restrict__ src, const int* __restrict__ dst, const float* __restrict__ u,
    const float* __restrict__ v, const int* __restrict__ tgt, const int* __restrict__ row_ptr,
    const int* __restrict__ csr_src, const int* __restrict__ row_ptr2,
    const int* __restrict__ csr_dst, const int* __restrict__ reach_row,
    float* __restrict__ ybuf, float* __restrict__ yout, int write_out,
    double* __restrict__ pe_slot, double* __restrict__ py_slot, int E, int N) {
  __shared__ double wsum[4];
  double term = 0.0;
  for (int e = blockIdx.x * blockDim.x + threadIdx.x; e < E; e += GB * 256) {
    float l = u[src[e]] + v[dst[e]];
    float a = 1.0f / (1.0f + expf(-l));
    float t = (float)tgt[e];
    float lp = fmaxf(logf(a), -100.0f);
    float l1 = fmaxf(logf(1.0f - a), -100.0f);
    term += (double)(t * lp + (1.0f - t) * l1);
  }
#pragma unroll
  for (int off = 32; off > 0; off >>= 1) term += __shfl_down(term, off);
  if ((threadIdx.x & 63) == 0) wsum[threadIdx.x >> 6] = term;
  __syncthreads();
  if (threadIdx.x == 0) pe_slot[blockIdx.x] = wsum[0] + wsum[1] + wsum[2] + wsum[3];
  __syncthreads();
  double c = 0.0;
  for (int n = blockIdx.x * blockDim.x + threadIdx.x; n < N; n += GB * 256) {
    float mu = -INFINITY, mv = -INFINITY;
    const int b1 = row_ptr[n], e1 = row_ptr[n + 1];
    for (int i = b1; i < e1; ++i) mu = fmaxf(mu, u[csr_src[i]]);
    const int b2 = row_ptr2[n], e2 = row_ptr2[n + 1];
    for (int i = b2; i < e2; ++i) mv = fmaxf(mv, v[csr_dst[i]]);
    float m = fmaxf(mu + v[n], u[n] + mv);
    float a = 1.0f / (1.0f + expf(-m));
    float yv = (a >= 0.8f) ? 1.0f : 0.0f;
    ybuf[n] = yv;
    if (write_out) yout[n] = yv;
    if ((float)reach_row[n] != yv) c = 100.0;
  }
#pragma unroll
  for (int off = 32; off > 0; off >>= 1) c += __shfl_down(c, off);
  if ((threadIdx.x & 63) == 0) wsum[threadIdx.x >> 6] = c;
  __syncthreads();
  if (threadIdx.x == 0) py_slot[blockIdx.x] = wsum[0] + wsum[1] + wsum[2] + wsum[3];
}

__global__ void k_final(const double* __restrict__ pe, const double* __restrict__ py,
                        float* __restrict__ out4, int N, int E, int T) {
  __shared__ double le[8], ly[8];
  int lane = threadIdx.x;  // 64 threads
  for (int it = 0; it < T; ++it) {
    double s = 0.0;
    for (int i = lane; i < GB; i += 64) s += pe[(size_t)it * GB + i];
#pragma unroll
    for (int off = 32; off > 0; off >>= 1) s += __shfl_down(s, off);
    if (lane == 0) le[it] = s;
    double s2 = 0.0;
    for (int i = lane; i < GB; i += 64) s2 += py[(size_t)it * GB + i];
#pragma unroll
    for (int off = 32; off > 0; off >>= 1) s2 += __shfl_down(s2, off);
    if (lane == 0) ly[it] = s2;
  }
  __syncthreads();
  if (lane == 0) {
    float loss_x = (float)(-le[T - 1] / (double)E);
    float loss_h = 0.0f;
    for (int i = 0; i < T - 1; ++i) loss_h += (float)(-le[i] / (double)E);
    float yl_x = (float)(ly[T - 1] / (double)N);
    float yl_h = 0.0f;
    for (int i = 0; i < T - 1; ++i) yl_h += (float)(ly[i] / (double)N);
    out4[0] = loss_x;
    out4[1] = loss_h;
    out4[2] = yl_x;
    out4[3] = yl_h;
  }
}

// ============ launch ============
extern "C" void kernel_launch(void* const* d_in, const int* in_sizes, int n_in,
                              void* d_out, int out_size, void* d_ws, size_t ws_size,
                              hipStream_t stream) {
  const float* pos = (const float*)d_in[0];
  const float* s = (const float*)d_in[1];
  const int* eidx = (const int*)d_in[2];
  const int* pi = (const int*)d_in[3];
  const int* pi_h = (const int*)d_in[4];
  const int* reach = (const int*)d_in[5];
  const float* W_enc = (const float*)d_in[6];
  const float* b_enc = (const float*)d_in[7];
  const float* W_msg = (const float*)d_in[8];
  const float* b_msg = (const float*)d_in[9];
  const float* W_self = (const float*)d_in[10];
  const float* W_agg = (const float*)d_in[11];
  const float* b_upd = (const float*)d_in[12];
  const float* W_dec = (const float*)d_in[13];
  const float* b_dec = (const float*)d_in[14];

  const int N = in_sizes[0];
  const int E = in_sizes[3];
  const int T = in_sizes[4] / in_sizes[3];
  const int Npad = ((N + 127) / 128) * 128;  // GEMM tiles unguarded
  const int* src = eidx;
  const int* dst = eidx + E;

  char* w = (char*)d_ws;
  auto alloc = [&](size_t bytes) {
    char* p = w;
    w += (bytes + 255) & ~(size_t)255;
    return p;
  };
  float* x = (float*)alloc((size_t)Npad * 256 * 4);    // [z | h], padded
  float* xw = (float*)alloc((size_t)Npad * 256 * 4);   // [msg_pre | self_pre], padded
  float* agg = (float*)alloc((size_t)N * 128 * 4);
  float* Wcat = (float*)alloc(256 * 256 * 4);
  float* bcat = (float*)alloc(256 * 4);
  float* u = (float*)alloc((size_t)N * 4);
  float* v = (float*)alloc((size_t)N * 4);
  float* ybuf = (float*)alloc((size_t)N * 4);
  int* cnt_d = (int*)alloc((size_t)N * 4);
  int* cnt_s = (int*)alloc((size_t)N * 4);
  int* row_ptr = (int*)alloc((size_t)(N + 1) * 4);
  int* row_ptr2 = (int*)alloc((size_t)(N + 1) * 4);
  int* csr_src = (int*)alloc((size_t)E * 4);
  int* csr_dst = (int*)alloc((size_t)E * 4);
  int* partial_d = (int*)alloc((size_t)CSR_B * N * 4);
  int* partial_s = (int*)alloc((size_t)CSR_B * N * 4);
  double* pe = (double*)alloc((size_t)T * GB * 8);
  double* py = (double*)alloc((size_t)T * GB * 8);

  float* outy = (float*)d_out;
  float* out4 = outy + N;

  k_build_w<<<256, 256, 0, stream>>>(W_msg, W_self, b_msg, Wcat, bcat);

  const size_t lds2 = (size_t)2 * ((N + 1) >> 1) * 4;  // ~80 KB
  k_hist2<<<CSR_B, 256, lds2, stream>>>(eidx, E, N, partial_d, partial_s);
  k_colscan2<<<(2 * N + 255) / 256, 256, 0, stream>>>(partial_d, cnt_d, partial_s, cnt_s, N);
  k_scan2both<<<1, 1024, 0, stream>>>(cnt_d, row_ptr, cnt_s, row_ptr2, N);
  k_scatter2<<<CSR_B, 256, lds2, stream>>>(eidx, E, N, partial_d, row_ptr, csr_src, partial_s,
                                           row_ptr2, csr_dst);

  const int Nh = (N + 1) / 2;
  const int NB = (Nh + 7) / 8;

  const float* sfeat = s;
  for (int it = 0; it < T; ++it) {
    k_encode<<<(N * 32 + 255) / 256, 256, 0, stream>>>(pos, sfeat, W_enc, b_enc, x, N);

    dim3 g1(Npad / 128, 8);
    if (it == 0)
      k_gemm_bf<128><<<g1, 128, 0, stream>>>(x, Wcat, bcat, xw);
    else
      k_gemm_bf<256><<<g1, 128, 0, stream>>>(x, Wcat, bcat, xw);

    k_aggmax<<<dim3(8, NB), 256, 0, stream>>>(xw, row_ptr, csr_src, agg, N, Nh);

    k_update2<<<(N + 31) / 32, 256, 0, stream>>>(agg, W_agg, b_upd, xw, W_dec, b_dec,
                                                 x, u, v, N);

    const int* tgt = (it < T - 1) ? (pi_h + (size_t)(it + 1) * E) : pi;
    const int* rrow = (it < T - 1) ? (reach + (size_t)(it + 1) * N) : (reach + (size_t)(T - 1) * N);
    k_losses<<<GB, 256, 0, stream>>>(src, dst, u, v, tgt, row_ptr, csr_src, row_ptr2, csr_dst,
                                     rrow, ybuf, outy, (it == T - 1) ? 1 : 0,
                                     pe + (size_t)it * GB, py + (size_t)it * GB, E, N);
    sfeat = ybuf;
  }
  k_final<<<1, 64, 0, stream>>>(pe, py, out4, N, E, T);
}

// Round 11
// 594.123 us; speedup vs baseline: 2.1297x; 1.0806x over previous
//
#include <hip/hip_runtime.h>

// ============ CSR build (both directions, one pass, no global atomics) ============
#define CSR_B 128

__global__ __launch_bounds__(256) void k_hist2(const int* __restrict__ eidx, int E, int N,
                                               int* __restrict__ partial_d,
                                               int* __restrict__ partial_s) {
  extern __shared__ unsigned int hist[];  // [2*nw]
  int nw = (N + 1) >> 1;
  for (int i = threadIdx.x; i < 2 * nw; i += blockDim.x) hist[i] = 0u;
  __syncthreads();
  const int* src = eidx;
  const int* dst = eidx + E;
  int chunk = (E + CSR_B - 1) / CSR_B;
  int beg = blockIdx.x * chunk, end = min(E, beg + chunk);
  for (int e = beg + threadIdx.x; e < end; e += blockDim.x) {
    int d = dst[e];
    atomicAdd(&hist[d >> 1], 1u << ((d & 1) * 16));
    int s = src[e];
    atomicAdd(&hist[nw + (s >> 1)], 1u << ((s & 1) * 16));
  }
  __syncthreads();
  for (int i = threadIdx.x; i < N; i += blockDim.x) {
    partial_d[(size_t)blockIdx.x * N + i] = (int)((hist[i >> 1] >> ((i & 1) * 16)) & 0xFFFFu);
    partial_s[(size_t)blockIdx.x * N + i] = (int)((hist[nw + (i >> 1)] >> ((i & 1) * 16)) & 0xFFFFu);
  }
}

__global__ __launch_bounds__(256) void k_colscan2(int* __restrict__ partial_d,
                                                  int* __restrict__ cnt_d,
                                                  int* __restrict__ partial_s,
                                                  int* __restrict__ cnt_s, int N) {
  int g = blockIdx.x * blockDim.x + threadIdx.x;
  int* partial;
  int* cnt;
  int bin;
  if (g < N) { partial = partial_d; cnt = cnt_d; bin = g; }
  else if (g < 2 * N) { partial = partial_s; cnt = cnt_s; bin = g - N; }
  else return;
  int run = 0;
  for (int b = 0; b < CSR_B; ++b) {
    int t = partial[(size_t)b * N + bin];
    partial[(size_t)b * N + bin] = run;
    run += t;
  }
  cnt[bin] = run;
}

__device__ __forceinline__ void scan_one(const int* __restrict__ cnt, int* __restrict__ rp,
                                         int N, int* sums) {
  int t = threadIdx.x;
  int chunk = (N + 1023) / 1024;
  int beg = t * chunk, end = min(N, beg + chunk);
  int s = 0;
  for (int i = beg; i < end; ++i) s += cnt[i];
  sums[t] = s;
  __syncthreads();
  for (int off = 1; off < 1024; off <<= 1) {
    int v = (t >= off) ? sums[t - off] : 0;
    __syncthreads();
    sums[t] += v;
    __syncthreads();
  }
  int run = (t > 0) ? sums[t - 1] : 0;
  if (t == 0) rp[0] = 0;
  for (int i = beg; i < end; ++i) { run += cnt[i]; rp[i + 1] = run; }
}

__global__ __launch_bounds__(1024) void k_scan2both(const int* __restrict__ cnt_d,
                                                    int* __restrict__ rp_d,
                                                    const int* __restrict__ cnt_s,
                                                    int* __restrict__ rp_s, int N) {
  __shared__ int sums[1024];
  scan_one(cnt_d, rp_d, N, sums);
  __syncthreads();
  scan_one(cnt_s, rp_s, N, sums);
}

__global__ __launch_bounds__(256) void k_scatter2(
    const int* __restrict__ eidx, int E, int N,
    const int* __restrict__ partial_d, const int* __restrict__ rp_d, int* __restrict__ csr_src,
    const int* __restrict__ partial_s, const int* __restrict__ rp_s, int* __restrict__ csr_dst) {
  extern __shared__ unsigned int cur[];  // [2*nw]
  int nw = (N + 1) >> 1;
  for (int i = threadIdx.x; i < 2 * nw; i += blockDim.x) cur[i] = 0u;
  __syncthreads();
  const int* src = eidx;
  const int* dst = eidx + E;
  int chunk = (E + CSR_B - 1) / CSR_B;
  int beg = blockIdx.x * chunk, end = min(E, beg + chunk);
  for (int e = beg + threadIdx.x; e < end; e += blockDim.x) {
    int d = dst[e], s = src[e];
    int shd = (d & 1) * 16;
    unsigned int old = atomicAdd(&cur[d >> 1], 1u << shd);
    csr_src[rp_d[d] + partial_d[(size_t)blockIdx.x * N + d] + (int)((old >> shd) & 0xFFFFu)] = s;
    int shs = (s & 1) * 16;
    unsigned int old2 = atomicAdd(&cur[nw + (s >> 1)], 1u << shs);
    csr_dst[rp_s[s] + partial_s[(size_t)blockIdx.x * N + s] + (int)((old2 >> shs) & 0xFFFFu)] = d;
  }
}

// ============ weights prep ============
__global__ void k_build_w(const float* __restrict__ W_msg, const float* __restrict__ W_self,
                          const float* __restrict__ b_msg, float* __restrict__ Wcat,
                          float* __restrict__ bcat) {
  int idx = blockIdx.x * blockDim.x + threadIdx.x;  // 256*256
  int k = idx >> 8, j = idx & 255;
  Wcat[idx] = (j < 128) ? W_msg[k * 128 + j] : W_self[k * 128 + (j - 128)];
  if (idx < 256) bcat[idx] = (idx < 128) ? b_msg[idx] : 0.0f;
}

// ============ encode: x[:,0:128] = relu([pos,sfeat]@W_enc + b_enc) ============
__global__ __launch_bounds__(256) void k_encode(
    const float* __restrict__ pos, const float* __restrict__ sfeat,
    const float* __restrict__ W_enc, const float* __restrict__ b_enc,
    float* __restrict__ x, int N) {
  int idx = blockIdx.x * blockDim.x + threadIdx.x;
  int n = idx >> 5, d4 = (idx & 31) << 2;
  if (n >= N) return;
  float p = pos[n], sf = sfeat[n];
  float4 we0 = *reinterpret_cast<const float4*>(&W_enc[d4]);
  float4 we1 = *reinterpret_cast<const float4*>(&W_enc[128 + d4]);
  float4 be  = *reinterpret_cast<const float4*>(&b_enc[d4]);
  float4 z;
  z.x = fmaxf(fmaf(p, we0.x, fmaf(sf, we1.x, be.x)), 0.f);
  z.y = fmaxf(fmaf(p, we0.y, fmaf(sf, we1.y, be.y)), 0.f);
  z.z = fmaxf(fmaf(p, we0.z, fmaf(sf, we1.z, be.z)), 0.f);
  z.w = fmaxf(fmaf(p, we0.w, fmaf(sf, we1.w, be.w)), 0.f);
  *reinterpret_cast<float4*>(&x[(size_t)n * 256 + d4]) = z;
}

// ============ GEMM (A-tile in LDS, B streamed from L2): xw = x @ Wcat + bcat ====
// Block: 32 rows x full 256 cols. x-tile (32 x KT) staged ONCE in LDS (the only
// barrier); x read exactly once from HBM (20 MB total). Wcat (256 KB, L2-hot in
// every XCD) streamed per k-quad with a 2-quad named-register pipeline.
// 128 threads = 4 row-groups x 32 col-groups; thread = 8 rows x 8 cols.
// Per k-quad/wave: 8 ds_read_b128 (96 cyc, 2-addr broadcast = conflict-free)
// vs 256 FMA (512 cyc) -> VALU-bound. KT=128 for it0 (h-half unused).
template <int KT>
__global__ __launch_bounds__(128) void k_gemm_al(
    const float* __restrict__ x, const float* __restrict__ Wc,
    const float* __restrict__ bias, float* __restrict__ C) {
  __shared__ float As[32][KT];
  const int m0 = blockIdx.x * 32;
  const int t = threadIdx.x;
#pragma unroll
  for (int it = 0; it < KT / 16; ++it) {
    int idx = t + it * 128;
    int row = idx / (KT / 4);
    int q = idx - row * (KT / 4);
    *reinterpret_cast<float4*>(&As[row][q * 4]) =
        *reinterpret_cast<const float4*>(&x[(size_t)(m0 + row) * 256 + q * 4]);
  }
  __syncthreads();  // the only barrier

  const int r0 = (t >> 5) * 8;   // 8 rows
  const int c0 = (t & 31) * 8;   // 8 cols
  const float* wp = Wc + c0;
  float acc[8][8] = {};
  float4 Bc0, Bc1, Bc2, Bc3, Bc4, Bc5, Bc6, Bc7;
  float4 Bn0, Bn1, Bn2, Bn3, Bn4, Bn5, Bn6, Bn7;

#define LOADB(R, kk)                                                              \
  R##0 = *reinterpret_cast<const float4*>(wp + (size_t)((kk) + 0) * 256);         \
  R##1 = *reinterpret_cast<const float4*>(wp + (size_t)((kk) + 0) * 256 + 4);     \
  R##2 = *reinterpret_cast<const float4*>(wp + (size_t)((kk) + 1) * 256);         \
  R##3 = *reinterpret_cast<const float4*>(wp + (size_t)((kk) + 1) * 256 + 4);     \
  R##4 = *reinterpret_cast<const float4*>(wp + (size_t)((kk) + 2) * 256);         \
  R##5 = *reinterpret_cast<const float4*>(wp + (size_t)((kk) + 2) * 256 + 4);     \
  R##6 = *reinterpret_cast<const float4*>(wp + (size_t)((kk) + 3) * 256);         \
  R##7 = *reinterpret_cast<const float4*>(wp + (size_t)((kk) + 3) * 256 + 4);

#define STEPJ(Blo, Bhi, CMP)                                                      \
  _Pragma("unroll") for (int i = 0; i < 8; ++i) {                                 \
    float av = a[i].CMP;                                                          \
    acc[i][0] = fmaf(av, Blo.x, acc[i][0]);                                       \
    acc[i][1] = fmaf(av, Blo.y, acc[i][1]);                                       \
    acc[i][2] = fmaf(av, Blo.z, acc[i][2]);                                       \
    acc[i][3] = fmaf(av, Blo.w, acc[i][3]);                                       \
    acc[i][4] = fmaf(av, Bhi.x, acc[i][4]);                                       \
    acc[i][5] = fmaf(av, Bhi.y, acc[i][5]);                                       \
    acc[i][6] = fmaf(av, Bhi.z, acc[i][6]);                                       \
    acc[i][7] = fmaf(av, Bhi.w, acc[i][7]);                                       \
  }

#define COMPQ(R, kq)                                                              \
  {                                                                               \
    float4 a[8];                                                                  \
    _Pragma("unroll") for (int i = 0; i < 8; ++i)                                 \
        a[i] = *reinterpret_cast<const float4*>(&As[r0 + i][(kq)]);               \
    STEPJ(R##0, R##1, x)                                                          \
    STEPJ(R##2, R##3, y)                                                          \
    STEPJ(R##4, R##5, z)                                                          \
    STEPJ(R##6, R##7, w)                                                          \
  }

  LOADB(Bc, 0);
  for (int kq = 0; kq < KT; kq += 8) {
    LOADB(Bn, kq + 4);
    COMPQ(Bc, kq);
    if (kq + 8 < KT) { LOADB(Bc, kq + 8); }
    COMPQ(Bn, kq + 4);
  }
#undef LOADB
#undef STEPJ
#undef COMPQ

  float4 blo = *reinterpret_cast<const float4*>(bias + c0);
  float4 bhi = *reinterpret_cast<const float4*>(bias + c0 + 4);
#pragma unroll
  for (int i = 0; i < 8; ++i) {
    float4 o0 = make_float4(acc[i][0] + blo.x, acc[i][1] + blo.y,
                            acc[i][2] + blo.z, acc[i][3] + blo.w);
    float4 o1 = make_float4(acc[i][4] + bhi.x, acc[i][5] + bhi.y,
                            acc[i][6] + bhi.z, acc[i][7] + bhi.w);
    float* cp = &C[(size_t)(m0 + r0 + i) * 256 + c0];
    *reinterpret_cast<float4*>(cp) = o0;
    *reinterpret_cast<float4*>(cp + 4) = o1;
  }
}

// ============ aggmax: feature-chunked for per-XCD L2 residence ============
__global__ __launch_bounds__(256) void k_aggmax(
    const float* __restrict__ xw, const int* __restrict__ row_ptr,
    const int* __restrict__ csr_src, float* __restrict__ agg, int N, int Nh) {
  const int cx = blockIdx.x & 7;
  const int chunk = cx & 3;
  const int half = cx >> 2;
  const int hw = threadIdx.x >> 5;
  const int sub = threadIdx.x & 31;
  const int node = half * Nh + blockIdx.y * 8 + hw;
  const int hi = half ? N : Nh;
  if (node >= hi) return;
  const float* base = xw + chunk * 32 + sub;
  const int beg = row_ptr[node], end = row_ptr[node + 1];
  float m0 = 0.f, m1 = 0.f, m2 = 0.f, m3 = 0.f;
  int i = beg;
  for (; i + 3 < end; i += 4) {
    int e0 = csr_src[i], e1 = csr_src[i + 1], e2 = csr_src[i + 2], e3 = csr_src[i + 3];
    float f0 = base[(size_t)e0 * 256];
    float f1 = base[(size_t)e1 * 256];
    float f2 = base[(size_t)e2 * 256];
    float f3 = base[(size_t)e3 * 256];
    m0 = fmaxf(m0, f0); m1 = fmaxf(m1, f1);
    m2 = fmaxf(m2, f2); m3 = fmaxf(m3, f3);
  }
  for (; i < end; ++i) m0 = fmaxf(m0, base[(size_t)csr_src[i] * 256]);
  m0 = fmaxf(fmaxf(m0, m1), fmaxf(m2, m3));
  agg[(size_t)node * 128 + chunk * 32 + sub] = m0;
}

// ==== update GEMM: h = relu(agg@W_agg + self + b_upd) -> x[:,128:256]; fused u,v ====
__global__ __launch_bounds__(256) void k_update2(
    const float* __restrict__ agg, const float* __restrict__ W_agg,
    const float* __restrict__ b_upd, const float* __restrict__ xw,
    const float* __restrict__ W_dec, const float* __restrict__ b_dec,
    float* __restrict__ x, float* __restrict__ u, float* __restrict__ v, int M) {
  __shared__ float AsT[32][33];   // [k][row] (transposed for b128 A reads)
  __shared__ float Bs[32][128];
  const int m0 = blockIdx.x * 32;
  const int t = threadIdx.x;
  const int ty = t >> 5, tx = t & 31;
  const int lar = t >> 3, lac = (t & 7) << 2;
  float acc[4][4] = {};
  for (int k0 = 0; k0 < 128; k0 += 32) {
    {
      float4 av = make_float4(0.f, 0.f, 0.f, 0.f);
      int row = m0 + lar;
      if (row < M) av = *reinterpret_cast<const float4*>(&agg[(size_t)row * 128 + k0 + lac]);
      AsT[lac + 0][lar] = av.x;
      AsT[lac + 1][lar] = av.y;
      AsT[lac + 2][lar] = av.z;
      AsT[lac + 3][lar] = av.w;
#pragma unroll
      for (int p = 0; p < 4; ++p) {
        int br = (t >> 5) + p * 8;
        *reinterpret_cast<float4*>(&Bs[br][tx * 4]) =
            *reinterpret_cast<const float4*>(&W_agg[(size_t)(k0 + br) * 128 + tx * 4]);
      }
    }
    __syncthreads();
#pragma unroll
    for (int k = 0; k < 32; ++k) {
      float4 a4 = *reinterpret_cast<const float4*>(&AsT[k][ty * 4]);
      float4 b4 = *reinterpret_cast<const float4*>(&Bs[k][tx * 4]);
      const float aa[4] = {a4.x, a4.y, a4.z, a4.w};
      const float bb[4] = {b4.x, b4.y, b4.z, b4.w};
#pragma unroll
      for (int j = 0; j < 4; ++j)
#pragma unroll
        for (int c = 0; c < 4; ++c) acc[j][c] = fmaf(aa[j], bb[c], acc[j][c]);
    }
    __syncthreads();
  }
  const float4 bu4 = *reinterpret_cast<const float4*>(&b_upd[tx * 4]);
  const float4 wdu = *reinterpret_cast<const float4*>(&W_dec[tx * 4]);
  const float4 wdv = *reinterpret_cast<const float4*>(&W_dec[128 + tx * 4]);
  const float bd = b_dec[0];
#pragma unroll
  for (int j = 0; j < 4; ++j) {
    int row = m0 + ty * 4 + j;
    if (row >= M) continue;
    float4 sf = *reinterpret_cast<const float4*>(&xw[(size_t)row * 256 + 128 + tx * 4]);
    float4 h4;
    h4.x = fmaxf(acc[j][0] + sf.x + bu4.x, 0.f);
    h4.y = fmaxf(acc[j][1] + sf.y + bu4.y, 0.f);
    h4.z = fmaxf(acc[j][2] + sf.z + bu4.z, 0.f);
    h4.w = fmaxf(acc[j][3] + sf.w + bu4.w, 0.f);
    *reinterpret_cast<float4*>(&x[(size_t)row * 256 + 128 + tx * 4]) = h4;  // h into x
    float up = h4.x * wdu.x + h4.y * wdu.y + h4.z * wdu.z + h4.w * wdu.w;
    float vp = h4.x * wdv.x + h4.y * wdv.y + h4.z * wdv.z + h4.w * wdv.w;
#pragma unroll
    for (int m = 16; m > 0; m >>= 1) {
      up += __shfl_xor(up, m);
      vp += __shfl_xor(vp, m);
    }
    if (tx == 0) {
      u[row] = up + bd;
      v[row] = vp;
    }
  }
}

// ============ fused losses: edge BCE partials + node y/max + y-BCE partials ============
#define GB 512
__global__ __launch_bounds__(256) void k_losses(
    const int* __restrict__ src, const int* __restrict__ dst, const float* __restrict__ u,
    const float* __restrict__ v, const int* __restrict__ tgt, const int* __restrict__ row_ptr,
    const int* __restrict__ csr_src, const int* __restrict__ row_ptr2,
    const int* __restrict__ csr_dst, const int* __restrict__ reach_row,
    float* __restrict__ ybuf, float* __restrict__ yout, int write_out,
    double* __restrict__ pe_slot, double* __restrict__ py_slot, int E, int N) {
  __shared__ double wsum[4];
  double term = 0.0;
  for (int e = blockIdx.x * blockDim.x + threadIdx.x; e < E; e += GB * 256) {
    float l = u[src[e]] + v[dst[e]];
    float a = 1.0f / (1.0f + expf(-l));
    float t = (float)tgt[e];
    float lp = fmaxf(logf(a), -100.0f);
    float l1 = fmaxf(logf(1.0f - a), -100.0f);
    term += (double)(t * lp + (1.0f - t) * l1);
  }
#pragma unroll
  for (int off = 32; off > 0; off >>= 1) term += __shfl_down(term, off);
  if ((threadIdx.x & 63) == 0) wsum[threadIdx.x >> 6] = term;
  __syncthreads();
  if (threadIdx.x == 0) pe_slot[blockIdx.x] = wsum[0] + wsum[1] + wsum[2] + wsum[3];
  __syncthreads();
  double c = 0.0;
  for (int n = blockIdx.x * blockDim.x + threadIdx.x; n < N; n += GB * 256) {
    float mu = -INFINITY, mv = -INFINITY;
    const int b1 = row_ptr[n], e1 = row_ptr[n + 1];
    for (int i = b1; i < e1; ++i) mu = fmaxf(mu, u[csr_src[i]]);
    const int b2 = row_ptr2[n], e2 = row_ptr2[n + 1];
    for (int i = b2; i < e2; ++i) mv = fmaxf(mv, v[csr_dst[i]]);
    float m = fmaxf(mu + v[n], u[n] + mv);
    float a = 1.0f / (1.0f + expf(-m));
    float yv = (a >= 0.8f) ? 1.0f : 0.0f;
    ybuf[n] = yv;
    if (write_out) yout[n] = yv;
    if ((float)reach_row[n] != yv) c = 100.0;
  }
#pragma unroll
  for (int off = 32; off > 0; off >>= 1) c += __shfl_down(c, off);
  if ((threadIdx.x & 63) == 0) wsum[threadIdx.x >> 6] = c;
  __syncthreads();
  if (threadIdx.x == 0) py_slot[blockIdx.x] = wsum[0] + wsum[1] + wsum[2] + wsum[3];
}

__global__ void k_final(const double* __restrict__ pe, const double* __restrict__ py,
                        float* __restrict__ out4, int N, int E, int T) {
  __shared__ double le[8], ly[8];
  int lane = threadIdx.x;  // 64 threads
  for (int it = 0; it < T; ++it) {
    double s = 0.0;
    for (int i = lane; i < GB; i += 64) s += pe[(size_t)it * GB + i];
#pragma unroll
    for (int off = 32; off > 0; off >>= 1) s += __shfl_down(s, off);
    if (lane == 0) le[it] = s;
    double s2 = 0.0;
    for (int i = lane; i < GB; i += 64) s2 += py[(size_t)it * GB + i];
#pragma unroll
    for (int off = 32; off > 0; off >>= 1) s2 += __shfl_down(s2, off);
    if (lane == 0) ly[it] = s2;
  }
  __syncthreads();
  if (lane == 0) {
    float loss_x = (float)(-le[T - 1] / (double)E);
    float loss_h = 0.0f;
    for (int i = 0; i < T - 1; ++i) loss_h += (float)(-le[i] / (double)E);
    float yl_x = (float)(ly[T - 1] / (double)N);
    float yl_h = 0.0f;
    for (int i = 0; i < T - 1; ++i) yl_h += (float)(ly[i] / (double)N);
    out4[0] = loss_x;
    out4[1] = loss_h;
    out4[2] = yl_x;
    out4[3] = yl_h;
  }
}

// ============ launch ============
extern "C" void kernel_launch(void* const* d_in, const int* in_sizes, int n_in,
                              void* d_out, int out_size, void* d_ws, size_t ws_size,
                              hipStream_t stream) {
  const float* pos = (const float*)d_in[0];
  const float* s = (const float*)d_in[1];
  const int* eidx = (const int*)d_in[2];
  const int* pi = (const int*)d_in[3];
  const int* pi_h = (const int*)d_in[4];
  const int* reach = (const int*)d_in[5];
  const float* W_enc = (const float*)d_in[6];
  const float* b_enc = (const float*)d_in[7];
  const float* W_msg = (const float*)d_in[8];
  const float* b_msg = (const float*)d_in[9];
  const float* W_self = (const float*)d_in[10];
  const float* W_agg = (const float*)d_in[11];
  const float* b_upd = (const float*)d_in[12];
  const float* W_dec = (const float*)d_in[13];
  const float* b_dec = (const float*)d_in[14];

  const int N = in_sizes[0];
  const int E = in_sizes[3];
  const int T = in_sizes[4] / in_sizes[3];
  const int Npad = ((N + 127) / 128) * 128;   // buffer padding
  const int Nt32 = ((N + 31) / 32) * 32;      // GEMM tile count basis
  const int* src = eidx;
  const int* dst = eidx + E;

  char* w = (char*)d_ws;
  auto alloc = [&](size_t bytes) {
    char* p = w;
    w += (bytes + 255) & ~(size_t)255;
    return p;
  };
  float* x = (float*)alloc((size_t)Npad * 256 * 4);    // [z | h], padded
  float* xw = (float*)alloc((size_t)Npad * 256 * 4);   // [msg_pre | self_pre], padded
  float* agg = (float*)alloc((size_t)N * 128 * 4);
  float* Wcat = (float*)alloc(256 * 256 * 4);
  float* bcat = (float*)alloc(256 * 4);
  float* u = (float*)alloc((size_t)N * 4);
  float* v = (float*)alloc((size_t)N * 4);
  float* ybuf = (float*)alloc((size_t)N * 4);
  int* cnt_d = (int*)alloc((size_t)N * 4);
  int* cnt_s = (int*)alloc((size_t)N * 4);
  int* row_ptr = (int*)alloc((size_t)(N + 1) * 4);
  int* row_ptr2 = (int*)alloc((size_t)(N + 1) * 4);
  int* csr_src = (int*)alloc((size_t)E * 4);
  int* csr_dst = (int*)alloc((size_t)E * 4);
  int* partial_d = (int*)alloc((size_t)CSR_B * N * 4);
  int* partial_s = (int*)alloc((size_t)CSR_B * N * 4);
  double* pe = (double*)alloc((size_t)T * GB * 8);
  double* py = (double*)alloc((size_t)T * GB * 8);

  float* outy = (float*)d_out;
  float* out4 = outy + N;

  k_build_w<<<256, 256, 0, stream>>>(W_msg, W_self, b_msg, Wcat, bcat);

  const size_t lds2 = (size_t)2 * ((N + 1) >> 1) * 4;  // ~80 KB
  k_hist2<<<CSR_B, 256, lds2, stream>>>(eidx, E, N, partial_d, partial_s);
  k_colscan2<<<(2 * N + 255) / 256, 256, 0, stream>>>(partial_d, cnt_d, partial_s, cnt_s, N);
  k_scan2both<<<1, 1024, 0, stream>>>(cnt_d, row_ptr, cnt_s, row_ptr2, N);
  k_scatter2<<<CSR_B, 256, lds2, stream>>>(eidx, E, N, partial_d, row_ptr, csr_src, partial_s,
                                           row_ptr2, csr_dst);

  const int Nh = (N + 1) / 2;
  const int NB = (Nh + 7) / 8;

  const float* sfeat = s;
  for (int it = 0; it < T; ++it) {
    k_encode<<<(N * 32 + 255) / 256, 256, 0, stream>>>(pos, sfeat, W_enc, b_enc, x, N);

    dim3 g1(Nt32 / 32);
    if (it == 0)
      k_gemm_al<128><<<g1, 128, 0, stream>>>(x, Wcat, bcat, xw);
    else
      k_gemm_al<256><<<g1, 128, 0, stream>>>(x, Wcat, bcat, xw);

    k_aggmax<<<dim3(8, NB), 256, 0, stream>>>(xw, row_ptr, csr_src, agg, N, Nh);

    k_update2<<<(N + 31) / 32, 256, 0, stream>>>(agg, W_agg, b_upd, xw, W_dec, b_dec,
                                                 x, u, v, N);

    const int* tgt = (it < T - 1) ? (pi_h + (size_t)(it + 1) * E) : pi;
    const int* rrow = (it < T - 1) ? (reach + (size_t)(it + 1) * N) : (reach + (size_t)(T - 1) * N);
    k_losses<<<GB, 256, 0, stream>>>(src, dst, u, v, tgt, row_ptr, csr_src, row_ptr2, csr_dst,
                                     rrow, ybuf, outy, (it == T - 1) ? 1 : 0,
                                     pe + (size_t)it * GB, py + (size_t)it * GB, E, N);
    sfeat = ybuf;
  }
  k_final<<<1, 64, 0, stream>>>(pe, py, out4, N, E, T);
}